// Round 4
// baseline (303.791 us; speedup 1.0000x reference)
//
#include <hip/hip_runtime.h>
#include <hip/hip_bf16.h>
#include <stdint.h>

// Bahdanau attention. B=32, T=2048, D=512, U=512.
// d_out: context[B,D] (16384 f32) then attention_weights[B,T,1] (65536 f32)

#define B_DIM 32
#define T_DIM 2048
#define D_DIM 512
#define U_DIM 512
#define M_DIM (B_DIM * T_DIM)   // 65536 rows

typedef short bf16x8 __attribute__((ext_vector_type(8)));
typedef float f32x4 __attribute__((ext_vector_type(4)));

__device__ __forceinline__ float fast_tanh(float x) {
    float e = __expf(2.0f * x);
    return 1.0f - __fdividef(2.0f, e + 1.0f);
}

// scalar RNE f32->bf16 (prep only)
__device__ __forceinline__ short bf16r(float x) {
    unsigned u = __float_as_uint(x);
    u += 0x7fffu + ((u >> 16) & 1u);
    return (short)(u >> 16);
}

// packed RNE conversion for the score hot loop (f32x4 pair -> 8 bf16)
__device__ __forceinline__ bf16x8 pack8v(f32x4 a, f32x4 b) {
    union { __hip_bfloat162 h[4]; bf16x8 v; } u;
    u.h[0] = __float22bfloat162_rn(make_float2(a[0], a[1]));
    u.h[1] = __float22bfloat162_rn(make_float2(a[2], a[3]));
    u.h[2] = __float22bfloat162_rn(make_float2(b[0], b[1]));
    u.h[3] = __float22bfloat162_rn(make_float2(b[2], b[3]));
    return u.v;
}

// ---------------------------------------------------------------------------
// W1T layout in 16-byte units (8 bf16 along k):
//   unit n = ut*16384 + kstep*1024 + kc*256 + uu
//   where u = ut*256+uu, k = kstep*32 + kc*8 + j.
// Score reads fragments DIRECTLY from L2 (W1T = 512 KiB, permanently
// cache-resident): lane (quad,l15), frag ui -> unit ut*16384 + ks*1024 +
// quad*256 + wc*128 + ui*16 + l15. Lanes are 256B-contiguous per quad.
// ---------------------------------------------------------------------------

// Kernel 1: prep. (unchanged)
__global__ void prep_kernel(const float* __restrict__ W1_w,
                            const float* __restrict__ W1_b,
                            const float* __restrict__ W2_w,
                            const float* __restrict__ W2_b,
                            const float* __restrict__ query,
                            unsigned short* __restrict__ W1T,
                            float* __restrict__ qb) {
    __shared__ float red[256];
    const int tid = threadIdx.x;
    if (blockIdx.x < 128) {
        int n = blockIdx.x * 256 + tid;   // unit id 0..32767
        int uu    = n & 255;
        int kc    = (n >> 8) & 3;
        int kstep = (n >> 10) & 15;
        int ut    = n >> 14;
        int u  = ut * 256 + uu;
        int k0 = kstep * 32 + kc * 8;
        bf16x8 pk;
#pragma unroll
        for (int j = 0; j < 8; ++j)
            pk[j] = bf16r(W1_w[(size_t)(k0 + j) * U_DIM + u]);  // coalesced in u
        ((bf16x8*)W1T)[n] = pk;
    } else {
        int bid = blockIdx.x - 128;       // 0..255
        int b  = bid >> 3;
        int ug = bid & 7;
        int u  = ug * 64 + (tid & 63);
        int dq = tid >> 6;                // 0..3 (128 d each)
        const float* q  = query + b * D_DIM + dq * 128;
        const float* w2 = W2_w + (size_t)(dq * 128) * U_DIM + u;
        float acc = 0.f;
#pragma unroll 8
        for (int d = 0; d < 128; ++d)
            acc += q[d] * w2[(size_t)d * U_DIM];
        red[tid] = acc;
        __syncthreads();
        if (tid < 64) {
            qb[b * U_DIM + u] = red[tid] + red[tid + 64] + red[tid + 128]
                              + red[tid + 192] + W2_b[u] + W1_b[u];
        }
    }
}

// ---------------------------------------------------------------------------
// Kernel 2: fused score GEMM. 2048 blocks x 256 thr (4 waves).
// Block: 64 m x 256 u (ut = bid&1). Waves: wr=w>>1 (32 m), wc=w&1 (128 u).
// Wave tile: acc[2][8] (64 AGPR), B-frag reused across 2 m-tiles.
//
// NO LDS, NO BARRIERS. Rationale: W1T (512 KiB, read-only) is permanently
// L2-resident -- staging it through LDS double-buffers + per-body barriers
// couples all waves into 2-3 barrier domains per CU and serializes on the
// LDS-DMA round trip (R0/R2/R3: three different sync schedules, identical
// 102-110 us, all pipes >80% idle => the sync machinery IS the bottleneck,
// common-mistake #7: don't LDS-stage what cache-fits). Here every wave runs
// free: per body 8 B-loads straight from L2 (coalesced 256B/quad segments)
// + 4 A-loads from HBM, 12 VMEM in flight per wave, 16 waves/CU.
// s_setprio(1) around the MFMA cluster: waves are now at independent
// phases (the m191 regime where setprio pays).
// ---------------------------------------------------------------------------
__global__ __launch_bounds__(256, 4) void score_kernel(
        const float* __restrict__ values,
        const unsigned short* __restrict__ W1T,
        const float* __restrict__ qb,
        const float* __restrict__ Vw,
        float* __restrict__ sP) {
    const int tid  = threadIdx.x;
    const int lane = tid & 63;
    const int w    = tid >> 6;       // 0..3
    const int l15  = lane & 15;
    const int quad = lane >> 4;
    const int wr   = w >> 1;         // 0..1 : 32 m-rows each
    const int wc   = w & 1;          // 0..1 : 128 u each
    const int ut   = blockIdx.x & 1;
    const int mb   = (blockIdx.x >> 1) * 64;
    const int b    = mb >> 11;       // 64-row chunks, 32 per batch

    const float* arow0 = values + (size_t)(mb + wr * 32 + l15) * D_DIM + quad * 8;
    const float* arow1 = arow0 + 16 * D_DIM;
    // per-lane B base: unit = ut*16384 + quad*256 + wc*128 + l15 (x8 shorts)
    const unsigned short* bbase =
        W1T + ((size_t)ut * 16384 + quad * 256 + wc * 128 + l15) * 8;

    f32x4 acc[2][8] = {};

#pragma unroll 1
    for (int ks = 0; ks < 16; ++ks) {
        // 8 B-fragments straight from L2 (independent, all in flight)
        const unsigned short* bks = bbase + (size_t)ks * 8192;  // ks*1024 units
        bf16x8 bfr[8];
#pragma unroll
        for (int ui = 0; ui < 8; ++ui)
            bfr[ui] = *(const bf16x8*)(bks + (size_t)ui * 128);  // ui*16 units

        // A for this step (HBM stream)
        f32x4 a00 = *(const f32x4*)(arow0 + ks * 32);
        f32x4 a01 = *(const f32x4*)(arow0 + ks * 32 + 4);
        f32x4 a10 = *(const f32x4*)(arow1 + ks * 32);
        f32x4 a11 = *(const f32x4*)(arow1 + ks * 32 + 4);

        bf16x8 a0 = pack8v(a00, a01);
        bf16x8 a1 = pack8v(a10, a11);
        __builtin_amdgcn_s_setprio(1);
#pragma unroll
        for (int ui = 0; ui < 8; ++ui) {
            acc[0][ui] = __builtin_amdgcn_mfma_f32_16x16x32_bf16(a0, bfr[ui], acc[0][ui], 0, 0, 0);
            acc[1][ui] = __builtin_amdgcn_mfma_f32_16x16x32_bf16(a1, bfr[ui], acc[1][ui], 0, 0, 0);
        }
        __builtin_amdgcn_s_setprio(0);
    }

    // ---- epilogue (once): tanh + Vw, reduce over u ----
    const int ub = ut * 256 + wc * 128 + l15;
    float sm[2][4] = {};
#pragma unroll
    for (int ui = 0; ui < 8; ++ui) {
        const int u = ub + ui * 16;
        const float qv = qb[b * U_DIM + u];
        const float vw = Vw[u];
#pragma unroll
        for (int mt = 0; mt < 2; ++mt)
#pragma unroll
            for (int r = 0; r < 4; ++r)
                sm[mt][r] += fast_tanh(acc[mt][ui][r] + qv) * vw;
    }
#pragma unroll
    for (int mt = 0; mt < 2; ++mt)
#pragma unroll
        for (int r = 0; r < 4; ++r) {
            float v = sm[mt][r];
            v += __shfl_xor(v, 1, 64);
            v += __shfl_xor(v, 2, 64);
            v += __shfl_xor(v, 4, 64);
            v += __shfl_xor(v, 8, 64);
            sm[mt][r] = v;
        }
    if (l15 == 0) {
        const int slice = ut * 2 + wc;
#pragma unroll
        for (int mt = 0; mt < 2; ++mt)
#pragma unroll
            for (int r = 0; r < 4; ++r)
                sP[(size_t)slice * M_DIM + mb + wr * 32 + mt * 16 + quad * 4 + r] = sm[mt][r];
    }
}

// ---------------------------------------------------------------------------
// Kernel 3: softmax over T per batch; sums the 4 score slices; writes weights.
// ---------------------------------------------------------------------------
__global__ void softmax_kernel(const float* __restrict__ sP,
                               float* __restrict__ out) {
    const int b = blockIdx.x;
    const int tid = threadIdx.x;

    float v[8];
    float mx = -1e30f;
#pragma unroll
    for (int i = 0; i < 8; ++i) {
        int m = b * T_DIM + i * 256 + tid;
        v[i] = sP[m] + sP[M_DIM + m] + sP[2 * M_DIM + m] + sP[3 * M_DIM + m];
        mx = fmaxf(mx, v[i]);
    }
#pragma unroll
    for (int off = 1; off < 64; off <<= 1)
        mx = fmaxf(mx, __shfl_xor(mx, off, 64));
    __shared__ float redm[4];
    if ((tid & 63) == 0) redm[tid >> 6] = mx;
    __syncthreads();
    mx = fmaxf(fmaxf(redm[0], redm[1]), fmaxf(redm[2], redm[3]));

    float sum = 0.f;
#pragma unroll
    for (int i = 0; i < 8; ++i) {
        v[i] = __expf(v[i] - mx);
        sum += v[i];
    }
#pragma unroll
    for (int off = 1; off < 64; off <<= 1)
        sum += __shfl_xor(sum, off, 64);
    __shared__ float reds[4];
    if ((tid & 63) == 0) reds[tid >> 6] = sum;
    __syncthreads();
    sum = reds[0] + reds[1] + reds[2] + reds[3];

    const float inv = 1.0f / sum;
#pragma unroll
    for (int i = 0; i < 8; ++i)
        out[B_DIM * D_DIM + b * T_DIM + i * 256 + tid] = v[i] * inv;
}

// ---------------------------------------------------------------------------
// Kernel 4: context partials. grid (32 tc, 32 b) x 256 thr. Block = 64 t x
// 512 d; two t-interleaved halves combined in LDS; partial -> P (no atomics).
// ---------------------------------------------------------------------------
__global__ void context_kernel(const float* __restrict__ values,
                               const float* __restrict__ weights,
                               float* __restrict__ P) {
    __shared__ float sw[64];
    __shared__ float red[512];
    const int tc = blockIdx.x;   // 0..31 (64 t each)
    const int b  = blockIdx.y;
    const int tid = threadIdx.x;
    const int d4 = tid & 127;    // float4 column
    const int th = tid >> 7;     // t-interleave half

    if (tid < 64) sw[tid] = weights[b * T_DIM + tc * 64 + tid];
    __syncthreads();

    const float4* vb = (const float4*)(values + ((size_t)b * T_DIM + tc * 64) * D_DIM) + d4;
    float4 acc = {0.f, 0.f, 0.f, 0.f};
#pragma unroll 8
    for (int i = th; i < 64; i += 2) {
        float wv = sw[i];
        float4 vv = vb[(size_t)i * 128];
        acc.x += wv * vv.x; acc.y += wv * vv.y;
        acc.z += wv * vv.z; acc.w += wv * vv.w;
    }
    if (th == 1) ((float4*)red)[d4] = acc;
    __syncthreads();
    if (th == 0) {
        float4 o = ((float4*)red)[d4];
        acc.x += o.x; acc.y += o.y; acc.z += o.z; acc.w += o.w;
        *(float4*)(P + ((size_t)(b * 32 + tc)) * 512 + d4 * 4) = acc;
    }
}

// Kernel 5: reduce the 32 t-chunk partials -> context output.
__global__ void reduce_kernel(const float* __restrict__ P,
                              float* __restrict__ ctx) {
    const int g = blockIdx.x * 256 + threadIdx.x;   // 0..16383
    const int b = g >> 9, d = g & 511;
    float s = 0.f;
#pragma unroll
    for (int tc = 0; tc < 32; ++tc)
        s += P[((size_t)(b * 32 + tc)) * 512 + d];
    ctx[g] = s;
}

// ---------------------------------------------------------------------------
extern "C" void kernel_launch(void* const* d_in, const int* in_sizes, int n_in,
                              void* d_out, int out_size, void* d_ws, size_t ws_size,
                              hipStream_t stream) {
    const float* values = (const float*)d_in[0];
    const float* query  = (const float*)d_in[1];
    const float* W1_w   = (const float*)d_in[2];
    const float* W1_b   = (const float*)d_in[3];
    const float* W2_w   = (const float*)d_in[4];
    const float* W2_b   = (const float*)d_in[5];
    const float* V_w    = (const float*)d_in[6];
    // V_b (d_in[7]) dropped: softmax is shift-invariant.

    float* out = (float*)d_out;

    unsigned char* ws = (unsigned char*)d_ws;
    unsigned short* W1T = (unsigned short*)(ws);             // 512 KiB
    float* qb = (float*)(ws + 524288);                       // 64 KiB
    float* sP = (float*)(ws + 524288 + 65536);               // 1 MiB (4 slices)
    float* P  = (float*)(ws + 524288 + 65536 + 1048576);     // 2 MiB

    prep_kernel<<<384, 256, 0, stream>>>(W1_w, W1_b, W2_w, W2_b, query, W1T, qb);
    score_kernel<<<2048, 256, 0, stream>>>(values, W1T, qb, V_w, sP);
    softmax_kernel<<<B_DIM, 256, 0, stream>>>(sP, out);
    context_kernel<<<dim3(32, B_DIM), 256, 0, stream>>>(values, out + B_DIM * D_DIM, P);
    reduce_kernel<<<64, 256, 0, stream>>>(P, out);
}

// Round 5
// 296.204 us; speedup vs baseline: 1.0256x; 1.0256x over previous
//
#include <hip/hip_runtime.h>
#include <hip/hip_bf16.h>
#include <stdint.h>

// Bahdanau attention. B=32, T=2048, D=512, U=512.
// d_out: context[B,D] (16384 f32) then attention_weights[B,T,1] (65536 f32)
//
// Structure (R5): 3 kernels.
//  1) prep: W1 -> bf16 W1T (MFMA layout) ; qb = query@W2 + biases.
//  2) fused: per 64-row chunk of values -- score GEMM (full 512 u),
//     chunk-local softmax partial (m_c, S_c), partial context
//     C_c[d] = sum_t e^{s_t-m_c} v[t,d] (v re-read from L2), raw scores -> sP.
//  3) combine: per batch -- global m,S from 32 chunks, rescale+reduce C_c,
//     write context; write weights = exp(s - m)/S from sP.
// Rationale: every structure tried (R0-R4) streams `values` at ~1.2 TB/s
// (pattern-capped, not fixable by scheduling). So move fewer bytes: values
// was read TWICE (score + context) -> read ONCE. 307 MB -> ~145 MB HBM.

#define B_DIM 32
#define T_DIM 2048
#define D_DIM 512
#define U_DIM 512
#define M_DIM (B_DIM * T_DIM)   // 65536 rows

typedef short bf16x8 __attribute__((ext_vector_type(8)));
typedef float f32x4 __attribute__((ext_vector_type(4)));

__device__ __forceinline__ float fast_tanh(float x) {
    float e = __expf(2.0f * x);
    return 1.0f - __fdividef(2.0f, e + 1.0f);
}

// scalar RNE f32->bf16 (prep only)
__device__ __forceinline__ short bf16r(float x) {
    unsigned u = __float_as_uint(x);
    u += 0x7fffu + ((u >> 16) & 1u);
    return (short)(u >> 16);
}

// packed RNE conversion for the score hot loop (f32x4 pair -> 8 bf16)
__device__ __forceinline__ bf16x8 pack8v(f32x4 a, f32x4 b) {
    union { __hip_bfloat162 h[4]; bf16x8 v; } u;
    u.h[0] = __float22bfloat162_rn(make_float2(a[0], a[1]));
    u.h[1] = __float22bfloat162_rn(make_float2(a[2], a[3]));
    u.h[2] = __float22bfloat162_rn(make_float2(b[0], b[1]));
    u.h[3] = __float22bfloat162_rn(make_float2(b[2], b[3]));
    return u.v;
}

// ---------------------------------------------------------------------------
// W1T layout in 16-byte units (8 bf16 along k):
//   unit n = ut*16384 + kstep*1024 + kc*256 + uu
//   where u = ut*256+uu, k = kstep*32 + kc*8 + j.
// Fused kernel reads fragments DIRECTLY from L2 (W1T = 512 KiB, permanently
// cache-resident): wave u-slice wc in 0..3 -> ut = wc>>1, (wc&1)*128;
// lane (quad,l15), frag ui -> unit ut*16384 + ks*1024 + quad*256 +
// (wc&1)*128 + ui*16 + l15. 256B-contiguous per quad. (R4-proven math.)
// ---------------------------------------------------------------------------

// Kernel 1: prep. (unchanged)
__global__ void prep_kernel(const float* __restrict__ W1_w,
                            const float* __restrict__ W1_b,
                            const float* __restrict__ W2_w,
                            const float* __restrict__ W2_b,
                            const float* __restrict__ query,
                            unsigned short* __restrict__ W1T,
                            float* __restrict__ qb) {
    __shared__ float red[256];
    const int tid = threadIdx.x;
    if (blockIdx.x < 128) {
        int n = blockIdx.x * 256 + tid;   // unit id 0..32767
        int uu    = n & 255;
        int kc    = (n >> 8) & 3;
        int kstep = (n >> 10) & 15;
        int ut    = n >> 14;
        int u  = ut * 256 + uu;
        int k0 = kstep * 32 + kc * 8;
        bf16x8 pk;
#pragma unroll
        for (int j = 0; j < 8; ++j)
            pk[j] = bf16r(W1_w[(size_t)(k0 + j) * U_DIM + u]);  // coalesced in u
        ((bf16x8*)W1T)[n] = pk;
    } else {
        int bid = blockIdx.x - 128;       // 0..255
        int b  = bid >> 3;
        int ug = bid & 7;
        int u  = ug * 64 + (tid & 63);
        int dq = tid >> 6;                // 0..3 (128 d each)
        const float* q  = query + b * D_DIM + dq * 128;
        const float* w2 = W2_w + (size_t)(dq * 128) * U_DIM + u;
        float acc = 0.f;
#pragma unroll 8
        for (int d = 0; d < 128; ++d)
            acc += q[d] * w2[(size_t)d * U_DIM];
        red[tid] = acc;
        __syncthreads();
        if (tid < 64) {
            qb[b * U_DIM + u] = red[tid] + red[tid + 64] + red[tid + 128]
                              + red[tid + 192] + W2_b[u] + W1_b[u];
        }
    }
}

// ---------------------------------------------------------------------------
// Kernel 2: fused score + chunk-softmax + partial-context.
// 1024 blocks x 512 thr (8 waves). Block = 64 m-rows x FULL 512 u.
// Waves: wr = w>>2 (0..1, 32 m each), wc = w&3 (0..3, 128 u each).
// Wave tile: acc[2][8] (R4-proven). B direct from L2, A direct from HBM.
// ---------------------------------------------------------------------------
__global__ __launch_bounds__(512, 4) void fused_kernel(
        const float* __restrict__ values,
        const unsigned short* __restrict__ W1T,
        const float* __restrict__ qb,
        const float* __restrict__ Vw,
        float* __restrict__ sP,
        float* __restrict__ Pms,
        float* __restrict__ Pctx) {
    __shared__ float sred[4][64];
    __shared__ float ew[64];
    __shared__ __align__(16) float red[4][512];

    const int tid  = threadIdx.x;
    const int lane = tid & 63;
    const int w    = tid >> 6;       // 0..7
    const int l15  = lane & 15;
    const int quad = lane >> 4;
    const int wr   = w >> 2;         // 0..1 : 32 m-rows each
    const int wc   = w & 3;          // 0..3 : 128 u each
    const int chunk = blockIdx.x;    // 0..1023 (= b*32 + c)
    const int mb   = chunk * 64;
    const int b    = mb >> 11;

    const float* arow0 = values + (size_t)(mb + wr * 32 + l15) * D_DIM + quad * 8;
    const float* arow1 = arow0 + 16 * D_DIM;
    // per-lane B base (R4 formula with ut = wc>>1, wc' = wc&1)
    const unsigned short* bbase =
        W1T + ((size_t)(wc >> 1) * 16384 + quad * 256 + (wc & 1) * 128 + l15) * 8;

    f32x4 acc[2][8] = {};

#pragma unroll 1
    for (int ks = 0; ks < 16; ++ks) {
        const unsigned short* bks = bbase + (size_t)ks * 8192;  // ks*1024 units
        bf16x8 bfr[8];
#pragma unroll
        for (int ui = 0; ui < 8; ++ui)
            bfr[ui] = *(const bf16x8*)(bks + (size_t)ui * 128);  // ui*16 units

        f32x4 a00 = *(const f32x4*)(arow0 + ks * 32);
        f32x4 a01 = *(const f32x4*)(arow0 + ks * 32 + 4);
        f32x4 a10 = *(const f32x4*)(arow1 + ks * 32);
        f32x4 a11 = *(const f32x4*)(arow1 + ks * 32 + 4);

        bf16x8 a0 = pack8v(a00, a01);
        bf16x8 a1 = pack8v(a10, a11);
        __builtin_amdgcn_s_setprio(1);
#pragma unroll
        for (int ui = 0; ui < 8; ++ui) {
            acc[0][ui] = __builtin_amdgcn_mfma_f32_16x16x32_bf16(a0, bfr[ui], acc[0][ui], 0, 0, 0);
            acc[1][ui] = __builtin_amdgcn_mfma_f32_16x16x32_bf16(a1, bfr[ui], acc[1][ui], 0, 0, 0);
        }
        __builtin_amdgcn_s_setprio(0);
    }

    // ---- per-wave u-slice score partial: tanh + Vw, reduce over u ----
    const int ub = wc * 128 + l15;
    float sm[2][4] = {};
#pragma unroll
    for (int ui = 0; ui < 8; ++ui) {
        const int u = ub + ui * 16;
        const float qv = qb[b * U_DIM + u];
        const float vw = Vw[u];
#pragma unroll
        for (int mt = 0; mt < 2; ++mt)
#pragma unroll
            for (int r = 0; r < 4; ++r)
                sm[mt][r] += fast_tanh(acc[mt][ui][r] + qv) * vw;
    }
#pragma unroll
    for (int mt = 0; mt < 2; ++mt)
#pragma unroll
        for (int r = 0; r < 4; ++r) {
            float v = sm[mt][r];
            v += __shfl_xor(v, 1, 64);
            v += __shfl_xor(v, 2, 64);
            v += __shfl_xor(v, 4, 64);
            v += __shfl_xor(v, 8, 64);
            sm[mt][r] = v;
        }
    if (l15 == 0) {
#pragma unroll
        for (int mt = 0; mt < 2; ++mt)
#pragma unroll
            for (int r = 0; r < 4; ++r)
                sred[wc][wr * 32 + mt * 16 + quad * 4 + r] = sm[mt][r];
    }
    __syncthreads();

    // ---- wave 0: full scores, chunk softmax partial (m_c, S_c, e_t) ----
    if (tid < 64) {
        float s = sred[0][tid] + sred[1][tid] + sred[2][tid] + sred[3][tid];
        sP[mb + tid] = s;                       // raw score for weights pass
        float m = s;
#pragma unroll
        for (int off = 1; off < 64; off <<= 1)
            m = fmaxf(m, __shfl_xor(m, off, 64));
        float e = __expf(s - m);
        ew[tid] = e;
        float S = e;
#pragma unroll
        for (int off = 1; off < 64; off <<= 1)
            S += __shfl_xor(S, off, 64);
        if (tid == 0) { Pms[chunk * 2] = m; Pms[chunk * 2 + 1] = S; }
    }
    __syncthreads();

    // ---- partial context: C_c[d] = sum_t e_t * v[t,d]; v rows hit L2 ----
    {
        const int d4 = tid & 127;    // float4 column (512 floats)
        const int th = tid >> 7;     // 0..3 : 16 contiguous rows each
        const float4* vb = (const float4*)(values + (size_t)(mb + th * 16) * D_DIM) + d4;
        float4 a = {0.f, 0.f, 0.f, 0.f};
#pragma unroll
        for (int i = 0; i < 16; ++i) {
            float e = ew[th * 16 + i];
            float4 v = vb[(size_t)i * 128];
            a.x += e * v.x; a.y += e * v.y;
            a.z += e * v.z; a.w += e * v.w;
        }
        ((float4*)red)[th * 128 + d4] = a;
    }
    __syncthreads();
    if (tid < 128) {
        float4 o0 = ((float4*)red)[tid];
        float4 o1 = ((float4*)red)[128 + tid];
        float4 o2 = ((float4*)red)[256 + tid];
        float4 o3 = ((float4*)red)[384 + tid];
        float4 o;
        o.x = o0.x + o1.x + o2.x + o3.x;
        o.y = o0.y + o1.y + o2.y + o3.y;
        o.z = o0.z + o1.z + o2.z + o3.z;
        o.w = o0.w + o1.w + o2.w + o3.w;
        *(float4*)(Pctx + (size_t)chunk * 512 + tid * 4) = o;
    }
}

// ---------------------------------------------------------------------------
// Kernel 3: combine. One block per batch (32 x 256 thr).
// Global m,S from 32 chunk partials; context = rescaled sum of C_c / S;
// weights = exp(s - m)/S from raw scores.
// ---------------------------------------------------------------------------
__global__ void combine_kernel(const float* __restrict__ Pctx,
                               const float* __restrict__ Pms,
                               const float* __restrict__ sP,
                               float* __restrict__ out) {
    __shared__ float sc[32];
    const int b   = blockIdx.x;
    const int tid = threadIdx.x;

    float m = -1e30f;
#pragma unroll
    for (int c = 0; c < 32; ++c)
        m = fmaxf(m, Pms[(b * 32 + c) * 2]);
    if (tid < 32) sc[tid] = __expf(Pms[(b * 32 + tid) * 2] - m);
    __syncthreads();
    float S = 0.f;
#pragma unroll
    for (int c = 0; c < 32; ++c)
        S += sc[c] * Pms[(b * 32 + c) * 2 + 1];
    const float invS = 1.0f / S;

    // context: each thread 2 d-columns
#pragma unroll
    for (int h = 0; h < 2; ++h) {
        const int d = h * 256 + tid;
        float a = 0.f;
#pragma unroll
        for (int c = 0; c < 32; ++c)
            a += sc[c] * Pctx[(size_t)(b * 32 + c) * 512 + d];
        out[b * D_DIM + d] = a * invS;
    }
    // weights: 2048 per batch, coalesced
#pragma unroll
    for (int j = 0; j < 8; ++j) {
        const int g = b * T_DIM + j * 256 + tid;
        out[B_DIM * D_DIM + g] = __expf(sP[g] - m) * invS;
    }
}

// ---------------------------------------------------------------------------
extern "C" void kernel_launch(void* const* d_in, const int* in_sizes, int n_in,
                              void* d_out, int out_size, void* d_ws, size_t ws_size,
                              hipStream_t stream) {
    const float* values = (const float*)d_in[0];
    const float* query  = (const float*)d_in[1];
    const float* W1_w   = (const float*)d_in[2];
    const float* W1_b   = (const float*)d_in[3];
    const float* W2_w   = (const float*)d_in[4];
    const float* W2_b   = (const float*)d_in[5];
    const float* V_w    = (const float*)d_in[6];
    // V_b (d_in[7]) dropped: softmax is shift-invariant.

    float* out = (float*)d_out;

    unsigned char* ws = (unsigned char*)d_ws;
    unsigned short* W1T = (unsigned short*)(ws);             // 512 KiB
    float* qb  = (float*)(ws + 524288);                      // 64 KiB
    float* sP  = (float*)(ws + 589824);                      // 256 KiB raw scores
    float* Pms = (float*)(ws + 851968);                      // 8 KiB (m_c, S_c)
    float* Pctx= (float*)(ws + 860160);                      // 2 MiB chunk contexts

    prep_kernel<<<384, 256, 0, stream>>>(W1_w, W1_b, W2_w, W2_b, query, W1T, qb);
    fused_kernel<<<1024, 512, 0, stream>>>(values, W1T, qb, V_w, sP, Pms, Pctx);
    combine_kernel<<<B_DIM, 256, 0, stream>>>(Pctx, Pms, sP, out);
}

// Round 6
// 274.060 us; speedup vs baseline: 1.1085x; 1.0808x over previous
//
#include <hip/hip_runtime.h>
#include <hip/hip_bf16.h>
#include <stdint.h>

// Bahdanau attention. B=32, T=2048, D=512, U=512.
// d_out: context[B,D] (16384 f32) then attention_weights[B,T,1] (65536 f32)
//
// R6 structure: 3 kernels.
//  1) prep: W1 -> bf16 W1T (MFMA layout); qb = query@W2 + biases.
//  2) fused: per 64-row chunk -- CONTIGUOUS staging of the chunk's values
//     (f32->bf16) into swizzled LDS, score GEMM from LDS(A) x L2(B),
//     chunk softmax partial, partial context (values re-read from L2),
//     raw scores -> sP.
//  3) combine: global m,S per batch; rescale C_c; weights from sP.
//
// WHY: R0-R5 all read `values` with per-lane row-scatter (16 x 64B segments
// per wave-instr, 2KB stride) -> empirically capped ~1.2 TB/s no matter the
// sync structure. context_kernel's contiguous pattern (1KB/wave-instr) hits
// ~6 TB/s on the same data. So the score A-read is restructured to stream
// contiguously through LDS. XOR swizzle (slot ^= row&7) kills the 1KB-row-
// stride bank collision on the fragment ds_read_b128 (T2 pattern, reg-staged
// writes so both sides swizzled per rule #21).

#define B_DIM 32
#define T_DIM 2048
#define D_DIM 512
#define U_DIM 512
#define M_DIM (B_DIM * T_DIM)   // 65536 rows

typedef short bf16x8 __attribute__((ext_vector_type(8)));
typedef float f32x4 __attribute__((ext_vector_type(4)));

__device__ __forceinline__ float fast_tanh(float x) {
    float e = __expf(2.0f * x);
    return 1.0f - __fdividef(2.0f, e + 1.0f);
}

// scalar RNE f32->bf16 (prep only)
__device__ __forceinline__ short bf16r(float x) {
    unsigned u = __float_as_uint(x);
    u += 0x7fffu + ((u >> 16) & 1u);
    return (short)(u >> 16);
}

// ---------------------------------------------------------------------------
// W1T layout in 16-byte units (8 bf16 along k):
//   unit n = ut*16384 + kstep*1024 + kc*256 + uu
//   where u = ut*256+uu, k = kstep*32 + kc*8 + j.
// Fused kernel reads B-fragments DIRECTLY from L2 (W1T = 512 KiB, resident):
// wave u-slice wc in 0..3 -> ut = wc>>1; lane (quad,l15), frag ui ->
// unit ut*16384 + ks*1024 + quad*256 + (wc&1)*128 + ui*16 + l15.
// 256B-contiguous per quad. (R4/R5-proven.)
// ---------------------------------------------------------------------------

// Kernel 1: prep. (unchanged)
__global__ void prep_kernel(const float* __restrict__ W1_w,
                            const float* __restrict__ W1_b,
                            const float* __restrict__ W2_w,
                            const float* __restrict__ W2_b,
                            const float* __restrict__ query,
                            unsigned short* __restrict__ W1T,
                            float* __restrict__ qb) {
    __shared__ float red[256];
    const int tid = threadIdx.x;
    if (blockIdx.x < 128) {
        int n = blockIdx.x * 256 + tid;   // unit id 0..32767
        int uu    = n & 255;
        int kc    = (n >> 8) & 3;
        int kstep = (n >> 10) & 15;
        int ut    = n >> 14;
        int u  = ut * 256 + uu;
        int k0 = kstep * 32 + kc * 8;
        bf16x8 pk;
#pragma unroll
        for (int j = 0; j < 8; ++j)
            pk[j] = bf16r(W1_w[(size_t)(k0 + j) * U_DIM + u]);  // coalesced in u
        ((bf16x8*)W1T)[n] = pk;
    } else {
        int bid = blockIdx.x - 128;       // 0..255
        int b  = bid >> 3;
        int ug = bid & 7;
        int u  = ug * 64 + (tid & 63);
        int dq = tid >> 6;                // 0..3 (128 d each)
        const float* q  = query + b * D_DIM + dq * 128;
        const float* w2 = W2_w + (size_t)(dq * 128) * U_DIM + u;
        float acc = 0.f;
#pragma unroll 8
        for (int d = 0; d < 128; ++d)
            acc += q[d] * w2[(size_t)d * U_DIM];
        red[tid] = acc;
        __syncthreads();
        if (tid < 64) {
            qb[b * U_DIM + u] = red[tid] + red[tid + 64] + red[tid + 128]
                              + red[tid + 192] + W2_b[u] + W1_b[u];
        }
    }
}

// ---------------------------------------------------------------------------
// Kernel 2: fused. 1024 blocks x 512 thr (8 waves).
// Block = 64 m-rows x FULL 512 u. Waves: wr=w>>2 (2x32 m), wc=w&3 (4x128 u).
// Wave tile acc[2][8] (R5-proven epilogue indices).
//
// LDS A-tile: Abuf[row][slot] -- row stride 1024B, 64 slots of 16B (8 bf16);
// stored slot' = slot ^ (row&7). Fragment read: row r = wr*32+mt*16+l15,
// slot = ks*4+quad -> lanes of a quad spread over 8 bank-groups (2-way, free).
// ---------------------------------------------------------------------------
__global__ __launch_bounds__(512, 4) void fused_kernel(
        const float* __restrict__ values,
        const unsigned short* __restrict__ W1T,
        const float* __restrict__ qb,
        const float* __restrict__ Vw,
        float* __restrict__ sP,
        float* __restrict__ Pms,
        float* __restrict__ Pctx) {
    __shared__ __align__(16) unsigned char Abuf[65536];   // 64 rows x 1024 B
    __shared__ float sred[4][64];
    __shared__ float ew[64];
    __shared__ __align__(16) float red[4][512];

    const int tid  = threadIdx.x;
    const int lane = tid & 63;
    const int w    = tid >> 6;       // 0..7
    const int l15  = lane & 15;
    const int quad = lane >> 4;
    const int wr   = w >> 2;         // 0..1 : 32 m-rows each
    const int wc   = w & 3;          // 0..3 : 128 u each
    const int chunk = blockIdx.x;    // 0..1023 (= b*32 + c)
    const int mb   = chunk * 64;
    const int b    = mb >> 11;

    // ---- phase 1: contiguous stage values[mb..mb+63][0..511] -> bf16 LDS ---
    {
        const float* src = values + (size_t)mb * D_DIM;
#pragma unroll 4
        for (int it = 0; it < 16; ++it) {
            int idx = it * 2048 + tid * 4;      // float index in 128KB region
            f32x4 v = *(const f32x4*)(src + idx);
            int row = idx >> 9;
            int k   = idx & 511;
            union { __hip_bfloat162 h[2]; unsigned long long u; } pk;
            pk.h[0] = __float22bfloat162_rn(make_float2(v[0], v[1]));
            pk.h[1] = __float22bfloat162_rn(make_float2(v[2], v[3]));
            int addr = row * 1024 + ((((k >> 3) ^ (row & 7)) << 4) | ((k & 7) * 2));
            *(unsigned long long*)(Abuf + addr) = pk.u;
        }
    }
    __syncthreads();

    // ---- phase 2: score GEMM: A from LDS, B from L2 ----
    const unsigned short* bbase =
        W1T + ((size_t)(wc >> 1) * 16384 + quad * 256 + (wc & 1) * 128 + l15) * 8;
    const int r0 = wr * 32 + l15;
    const int r1 = r0 + 16;

    f32x4 acc[2][8] = {};

#pragma unroll 1
    for (int ks = 0; ks < 16; ++ks) {
        const unsigned short* bks = bbase + (size_t)ks * 8192;  // ks*1024 units
        bf16x8 bfr[8];
#pragma unroll
        for (int ui = 0; ui < 8; ++ui)
            bfr[ui] = *(const bf16x8*)(bks + (size_t)ui * 128);  // ui*16 units

        const int slot = ks * 4 + quad;
        bf16x8 a0 = *(const bf16x8*)(Abuf + r0 * 1024 + ((slot ^ (r0 & 7)) << 4));
        bf16x8 a1 = *(const bf16x8*)(Abuf + r1 * 1024 + ((slot ^ (r1 & 7)) << 4));

        __builtin_amdgcn_s_setprio(1);
#pragma unroll
        for (int ui = 0; ui < 8; ++ui) {
            acc[0][ui] = __builtin_amdgcn_mfma_f32_16x16x32_bf16(a0, bfr[ui], acc[0][ui], 0, 0, 0);
            acc[1][ui] = __builtin_amdgcn_mfma_f32_16x16x32_bf16(a1, bfr[ui], acc[1][ui], 0, 0, 0);
        }
        __builtin_amdgcn_s_setprio(0);
    }

    // ---- per-wave u-slice score partial: tanh + Vw, reduce over u ----
    const int ub = wc * 128 + l15;
    float sm[2][4] = {};
#pragma unroll
    for (int ui = 0; ui < 8; ++ui) {
        const int u = ub + ui * 16;
        const float qv = qb[b * U_DIM + u];
        const float vw = Vw[u];
#pragma unroll
        for (int mt = 0; mt < 2; ++mt)
#pragma unroll
            for (int r = 0; r < 4; ++r)
                sm[mt][r] += fast_tanh(acc[mt][ui][r] + qv) * vw;
    }
#pragma unroll
    for (int mt = 0; mt < 2; ++mt)
#pragma unroll
        for (int r = 0; r < 4; ++r) {
            float v = sm[mt][r];
            v += __shfl_xor(v, 1, 64);
            v += __shfl_xor(v, 2, 64);
            v += __shfl_xor(v, 4, 64);
            v += __shfl_xor(v, 8, 64);
            sm[mt][r] = v;
        }
    if (l15 == 0) {
#pragma unroll
        for (int mt = 0; mt < 2; ++mt)
#pragma unroll
            for (int r = 0; r < 4; ++r)
                sred[wc][wr * 32 + mt * 16 + quad * 4 + r] = sm[mt][r];
    }
    __syncthreads();

    // ---- wave 0: full scores, chunk softmax partial (m_c, S_c, e_t) ----
    if (tid < 64) {
        float s = sred[0][tid] + sred[1][tid] + sred[2][tid] + sred[3][tid];
        sP[mb + tid] = s;                       // raw score for weights pass
        float m = s;
#pragma unroll
        for (int off = 1; off < 64; off <<= 1)
            m = fmaxf(m, __shfl_xor(m, off, 64));
        float e = __expf(s - m);
        ew[tid] = e;
        float S = e;
#pragma unroll
        for (int off = 1; off < 64; off <<= 1)
            S += __shfl_xor(S, off, 64);
        if (tid == 0) { Pms[chunk * 2] = m; Pms[chunk * 2 + 1] = S; }
    }
    __syncthreads();

    // ---- partial context: C_c[d] = sum_t e_t * v[t,d]; v rows hit L2 ----
    {
        const int d4 = tid & 127;    // float4 column (512 floats)
        const int th = tid >> 7;     // 0..3 : 16 contiguous rows each
        const float4* vb = (const float4*)(values + (size_t)(mb + th * 16) * D_DIM) + d4;
        float4 a = {0.f, 0.f, 0.f, 0.f};
#pragma unroll
        for (int i = 0; i < 16; ++i) {
            float e = ew[th * 16 + i];
            float4 v = vb[(size_t)i * 128];
            a.x += e * v.x; a.y += e * v.y;
            a.z += e * v.z; a.w += e * v.w;
        }
        ((float4*)red)[th * 128 + d4] = a;
    }
    __syncthreads();
    if (tid < 128) {
        float4 o0 = ((float4*)red)[tid];
        float4 o1 = ((float4*)red)[128 + tid];
        float4 o2 = ((float4*)red)[256 + tid];
        float4 o3 = ((float4*)red)[384 + tid];
        float4 o;
        o.x = o0.x + o1.x + o2.x + o3.x;
        o.y = o0.y + o1.y + o2.y + o3.y;
        o.z = o0.z + o1.z + o2.z + o3.z;
        o.w = o0.w + o1.w + o2.w + o3.w;
        *(float4*)(Pctx + (size_t)chunk * 512 + tid * 4) = o;
    }
}

// ---------------------------------------------------------------------------
// Kernel 3: combine. 256 blocks x 64 thr: b = bid>>3, part p = bid&7.
// Global m,S from 32 chunk partials; context d-slice p*64..p*64+63;
// weights t-slice p*256..p*256+255.
// ---------------------------------------------------------------------------
__global__ void combine_kernel(const float* __restrict__ Pctx,
                               const float* __restrict__ Pms,
                               const float* __restrict__ sP,
                               float* __restrict__ out) {
    const int bid = blockIdx.x;
    const int b   = bid >> 3;
    const int p   = bid & 7;
    const int tid = threadIdx.x;    // 0..63

    float m = -1e30f;
#pragma unroll
    for (int c = 0; c < 32; ++c)
        m = fmaxf(m, Pms[(b * 32 + c) * 2]);
    float ec[32];
    float S = 0.f;
#pragma unroll
    for (int c = 0; c < 32; ++c) {
        ec[c] = __expf(Pms[(b * 32 + c) * 2] - m);
        S += ec[c] * Pms[(b * 32 + c) * 2 + 1];
    }
    const float invS = 1.0f / S;

    // context slice
    {
        const int d = p * 64 + tid;
        float a = 0.f;
#pragma unroll
        for (int c = 0; c < 32; ++c)
            a += ec[c] * Pctx[(size_t)(b * 32 + c) * 512 + d];
        out[b * D_DIM + d] = a * invS;
    }
    // weights slice (256 t per block, coalesced)
#pragma unroll
    for (int j = 0; j < 4; ++j) {
        const int g = b * T_DIM + p * 256 + j * 64 + tid;
        out[B_DIM * D_DIM + g] = __expf(sP[g] - m) * invS;
    }
}

// ---------------------------------------------------------------------------
extern "C" void kernel_launch(void* const* d_in, const int* in_sizes, int n_in,
                              void* d_out, int out_size, void* d_ws, size_t ws_size,
                              hipStream_t stream) {
    const float* values = (const float*)d_in[0];
    const float* query  = (const float*)d_in[1];
    const float* W1_w   = (const float*)d_in[2];
    const float* W1_b   = (const float*)d_in[3];
    const float* W2_w   = (const float*)d_in[4];
    const float* W2_b   = (const float*)d_in[5];
    const float* V_w    = (const float*)d_in[6];
    // V_b (d_in[7]) dropped: softmax is shift-invariant.

    float* out = (float*)d_out;

    unsigned char* ws = (unsigned char*)d_ws;
    unsigned short* W1T = (unsigned short*)(ws);             // 512 KiB
    float* qb  = (float*)(ws + 524288);                      // 64 KiB
    float* sP  = (float*)(ws + 589824);                      // 256 KiB raw scores
    float* Pms = (float*)(ws + 851968);                      // 8 KiB (m_c, S_c)
    float* Pctx= (float*)(ws + 860160);                      // 2 MiB chunk contexts

    prep_kernel<<<384, 256, 0, stream>>>(W1_w, W1_b, W2_w, W2_b, query, W1T, qb);
    fused_kernel<<<1024, 512, 0, stream>>>(values, W1T, qb, V_w, sP, Pms, Pctx);
    combine_kernel<<<256, 64, 0, stream>>>(Pctx, Pms, sP, out);
}

// Round 7
// 264.553 us; speedup vs baseline: 1.1483x; 1.0359x over previous
//
#include <hip/hip_runtime.h>
#include <hip/hip_bf16.h>
#include <stdint.h>

// Bahdanau attention. B=32, T=2048, D=512, U=512.
// d_out: context[B,D] (16384 f32) then attention_weights[B,T,1] (65536 f32)
//
// R7 = R6 skeleton (best so far) + three micro-fixes in fused_kernel:
//  (a) per-block ks rotation -- decorrelate the cross-block same-address
//      W1T read bursts (every resident block was reading identical B
//      addresses at identical loop indices -> L2 bank/line hotspot);
//  (b) sched_barrier(0) fence between the {8 B-loads + 2 A ds_reads} batch
//      and the MFMA cluster -- forbid the compiler from interleaving loads
//      between MFMAs (which serializes 8x L2 latency per ks instead of 1x);
//  (c) phase-1 unroll 8 -- 8 HBM loads in flight per thread during staging.

#define B_DIM 32
#define T_DIM 2048
#define D_DIM 512
#define U_DIM 512
#define M_DIM (B_DIM * T_DIM)   // 65536 rows

typedef short bf16x8 __attribute__((ext_vector_type(8)));
typedef float f32x4 __attribute__((ext_vector_type(4)));

__device__ __forceinline__ float fast_tanh(float x) {
    float e = __expf(2.0f * x);
    return 1.0f - __fdividef(2.0f, e + 1.0f);
}

// scalar RNE f32->bf16 (prep only)
__device__ __forceinline__ short bf16r(float x) {
    unsigned u = __float_as_uint(x);
    u += 0x7fffu + ((u >> 16) & 1u);
    return (short)(u >> 16);
}

// ---------------------------------------------------------------------------
// W1T layout in 16-byte units (8 bf16 along k):
//   unit n = ut*16384 + kstep*1024 + kc*256 + uu
//   where u = ut*256+uu, k = kstep*32 + kc*8 + j.
// Fused kernel reads B-fragments DIRECTLY from L2 (W1T = 512 KiB, resident):
// wave u-slice wc in 0..3 -> ut = wc>>1; lane (quad,l15), frag ui ->
// unit ut*16384 + ks*1024 + quad*256 + (wc&1)*128 + ui*16 + l15.
// 256B-contiguous per quad. (R4/R5/R6-proven.)
// ---------------------------------------------------------------------------

// Kernel 1: prep. (unchanged)
__global__ void prep_kernel(const float* __restrict__ W1_w,
                            const float* __restrict__ W1_b,
                            const float* __restrict__ W2_w,
                            const float* __restrict__ W2_b,
                            const float* __restrict__ query,
                            unsigned short* __restrict__ W1T,
                            float* __restrict__ qb) {
    __shared__ float red[256];
    const int tid = threadIdx.x;
    if (blockIdx.x < 128) {
        int n = blockIdx.x * 256 + tid;   // unit id 0..32767
        int uu    = n & 255;
        int kc    = (n >> 8) & 3;
        int kstep = (n >> 10) & 15;
        int ut    = n >> 14;
        int u  = ut * 256 + uu;
        int k0 = kstep * 32 + kc * 8;
        bf16x8 pk;
#pragma unroll
        for (int j = 0; j < 8; ++j)
            pk[j] = bf16r(W1_w[(size_t)(k0 + j) * U_DIM + u]);  // coalesced in u
        ((bf16x8*)W1T)[n] = pk;
    } else {
        int bid = blockIdx.x - 128;       // 0..255
        int b  = bid >> 3;
        int ug = bid & 7;
        int u  = ug * 64 + (tid & 63);
        int dq = tid >> 6;                // 0..3 (128 d each)
        const float* q  = query + b * D_DIM + dq * 128;
        const float* w2 = W2_w + (size_t)(dq * 128) * U_DIM + u;
        float acc = 0.f;
#pragma unroll 8
        for (int d = 0; d < 128; ++d)
            acc += q[d] * w2[(size_t)d * U_DIM];
        red[tid] = acc;
        __syncthreads();
        if (tid < 64) {
            qb[b * U_DIM + u] = red[tid] + red[tid + 64] + red[tid + 128]
                              + red[tid + 192] + W2_b[u] + W1_b[u];
        }
    }
}

// ---------------------------------------------------------------------------
// Kernel 2: fused. 1024 blocks x 512 thr (8 waves).
// Block = 64 m-rows x FULL 512 u. Waves: wr=w>>2 (2x32 m), wc=w&3 (4x128 u).
// Wave tile acc[2][8] (proven epilogue indices).
//
// LDS A-tile: Abuf[row][slot] -- row stride 1024B, 64 slots of 16B (8 bf16);
// stored slot' = slot ^ (row&7). Fragment read: row r = wr*32+mt*16+l15,
// slot = ks*4+quad -> lanes of a quad spread over 8 bank-groups.
// ---------------------------------------------------------------------------
__global__ __launch_bounds__(512, 4) void fused_kernel(
        const float* __restrict__ values,
        const unsigned short* __restrict__ W1T,
        const float* __restrict__ qb,
        const float* __restrict__ Vw,
        float* __restrict__ sP,
        float* __restrict__ Pms,
        float* __restrict__ Pctx) {
    __shared__ __align__(16) unsigned char Abuf[65536];   // 64 rows x 1024 B
    __shared__ float sred[4][64];
    __shared__ float ew[64];
    __shared__ __align__(16) float red[4][512];

    const int tid  = threadIdx.x;
    const int lane = tid & 63;
    const int w    = tid >> 6;       // 0..7
    const int l15  = lane & 15;
    const int quad = lane >> 4;
    const int wr   = w >> 2;         // 0..1 : 32 m-rows each
    const int wc   = w & 3;          // 0..3 : 128 u each
    const int chunk = blockIdx.x;    // 0..1023 (= b*32 + c)
    const int mb   = chunk * 64;
    const int b    = mb >> 11;

    // ---- phase 1: contiguous stage values[mb..mb+63][0..511] -> bf16 LDS ---
    {
        const float* src = values + (size_t)mb * D_DIM;
#pragma unroll 8
        for (int it = 0; it < 16; ++it) {
            int idx = it * 2048 + tid * 4;      // float index in 128KB region
            f32x4 v = *(const f32x4*)(src + idx);
            int row = idx >> 9;
            int k   = idx & 511;
            union { __hip_bfloat162 h[2]; unsigned long long u; } pk;
            pk.h[0] = __float22bfloat162_rn(make_float2(v[0], v[1]));
            pk.h[1] = __float22bfloat162_rn(make_float2(v[2], v[3]));
            int addr = row * 1024 + ((((k >> 3) ^ (row & 7)) << 4) | ((k & 7) * 2));
            *(unsigned long long*)(Abuf + addr) = pk.u;
        }
    }
    __syncthreads();

    // ---- phase 2: score GEMM: A from LDS, B from L2 ----
    const unsigned short* bbase =
        W1T + ((size_t)(wc >> 1) * 16384 + quad * 256 + (wc & 1) * 128 + l15) * 8;
    const int r0 = wr * 32 + l15;
    const int r1 = r0 + 16;
    const int ksrot = chunk & 15;    // per-block rotation: decorrelate W1T reads

    f32x4 acc[2][8] = {};

#pragma unroll 1
    for (int it = 0; it < 16; ++it) {
        const int ks = (it + ksrot) & 15;
        const unsigned short* bks = bbase + (size_t)ks * 8192;  // ks*1024 units
        bf16x8 bfr[8];
#pragma unroll
        for (int ui = 0; ui < 8; ++ui)
            bfr[ui] = *(const bf16x8*)(bks + (size_t)ui * 128);  // ui*16 units

        const int slot = ks * 4 + quad;
        bf16x8 a0 = *(const bf16x8*)(Abuf + r0 * 1024 + ((slot ^ (r0 & 7)) << 4));
        bf16x8 a1 = *(const bf16x8*)(Abuf + r1 * 1024 + ((slot ^ (r1 & 7)) << 4));

        // fence: keep ALL loads batched above the MFMA cluster; the compiler
        // then emits partial vmcnt(N) waits (consume bfr in issue order).
        __builtin_amdgcn_sched_barrier(0);

        __builtin_amdgcn_s_setprio(1);
#pragma unroll
        for (int ui = 0; ui < 8; ++ui) {
            acc[0][ui] = __builtin_amdgcn_mfma_f32_16x16x32_bf16(a0, bfr[ui], acc[0][ui], 0, 0, 0);
            acc[1][ui] = __builtin_amdgcn_mfma_f32_16x16x32_bf16(a1, bfr[ui], acc[1][ui], 0, 0, 0);
        }
        __builtin_amdgcn_s_setprio(0);
        __builtin_amdgcn_sched_barrier(0);
    }

    // ---- per-wave u-slice score partial: tanh + Vw, reduce over u ----
    const int ub = wc * 128 + l15;
    float sm[2][4] = {};
#pragma unroll
    for (int ui = 0; ui < 8; ++ui) {
        const int u = ub + ui * 16;
        const float qv = qb[b * U_DIM + u];
        const float vw = Vw[u];
#pragma unroll
        for (int mt = 0; mt < 2; ++mt)
#pragma unroll
            for (int r = 0; r < 4; ++r)
                sm[mt][r] += fast_tanh(acc[mt][ui][r] + qv) * vw;
    }
#pragma unroll
    for (int mt = 0; mt < 2; ++mt)
#pragma unroll
        for (int r = 0; r < 4; ++r) {
            float v = sm[mt][r];
            v += __shfl_xor(v, 1, 64);
            v += __shfl_xor(v, 2, 64);
            v += __shfl_xor(v, 4, 64);
            v += __shfl_xor(v, 8, 64);
            sm[mt][r] = v;
        }
    if (l15 == 0) {
#pragma unroll
        for (int mt = 0; mt < 2; ++mt)
#pragma unroll
            for (int r = 0; r < 4; ++r)
                sred[wc][wr * 32 + mt * 16 + quad * 4 + r] = sm[mt][r];
    }
    __syncthreads();

    // ---- wave 0: full scores, chunk softmax partial (m_c, S_c, e_t) ----
    if (tid < 64) {
        float s = sred[0][tid] + sred[1][tid] + sred[2][tid] + sred[3][tid];
        sP[mb + tid] = s;                       // raw score for weights pass
        float m = s;
#pragma unroll
        for (int off = 1; off < 64; off <<= 1)
            m = fmaxf(m, __shfl_xor(m, off, 64));
        float e = __expf(s - m);
        ew[tid] = e;
        float S = e;
#pragma unroll
        for (int off = 1; off < 64; off <<= 1)
            S += __shfl_xor(S, off, 64);
        if (tid == 0) { Pms[chunk * 2] = m; Pms[chunk * 2 + 1] = S; }
    }
    __syncthreads();

    // ---- partial context: C_c[d] = sum_t e_t * v[t,d]; v rows hit L2 ----
    {
        const int d4 = tid & 127;    // float4 column (512 floats)
        const int th = tid >> 7;     // 0..3 : 16 contiguous rows each
        const float4* vb = (const float4*)(values + (size_t)(mb + th * 16) * D_DIM) + d4;
        float4 a = {0.f, 0.f, 0.f, 0.f};
#pragma unroll
        for (int i = 0; i < 16; ++i) {
            float e = ew[th * 16 + i];
            float4 v = vb[(size_t)i * 128];
            a.x += e * v.x; a.y += e * v.y;
            a.z += e * v.z; a.w += e * v.w;
        }
        ((float4*)red)[th * 128 + d4] = a;
    }
    __syncthreads();
    if (tid < 128) {
        float4 o0 = ((float4*)red)[tid];
        float4 o1 = ((float4*)red)[128 + tid];
        float4 o2 = ((float4*)red)[256 + tid];
        float4 o3 = ((float4*)red)[384 + tid];
        float4 o;
        o.x = o0.x + o1.x + o2.x + o3.x;
        o.y = o0.y + o1.y + o2.y + o3.y;
        o.z = o0.z + o1.z + o2.z + o3.z;
        o.w = o0.w + o1.w + o2.w + o3.w;
        *(float4*)(Pctx + (size_t)chunk * 512 + tid * 4) = o;
    }
}

// ---------------------------------------------------------------------------
// Kernel 3: combine. 256 blocks x 64 thr: b = bid>>3, part p = bid&7.
// Global m,S from 32 chunk partials; context d-slice p*64..p*64+63;
// weights t-slice p*256..p*256+255.
// ---------------------------------------------------------------------------
__global__ void combine_kernel(const float* __restrict__ Pctx,
                               const float* __restrict__ Pms,
                               const float* __restrict__ sP,
                               float* __restrict__ out) {
    const int bid = blockIdx.x;
    const int b   = bid >> 3;
    const int p   = bid & 7;
    const int tid = threadIdx.x;    // 0..63

    float m = -1e30f;
#pragma unroll
    for (int c = 0; c < 32; ++c)
        m = fmaxf(m, Pms[(b * 32 + c) * 2]);
    float ec[32];
    float S = 0.f;
#pragma unroll
    for (int c = 0; c < 32; ++c) {
        ec[c] = __expf(Pms[(b * 32 + c) * 2] - m);
        S += ec[c] * Pms[(b * 32 + c) * 2 + 1];
    }
    const float invS = 1.0f / S;

    // context slice
    {
        const int d = p * 64 + tid;
        float a = 0.f;
#pragma unroll
        for (int c = 0; c < 32; ++c)
            a += ec[c] * Pctx[(size_t)(b * 32 + c) * 512 + d];
        out[b * D_DIM + d] = a * invS;
    }
    // weights slice (256 t per block, coalesced)
#pragma unroll
    for (int j = 0; j < 4; ++j) {
        const int g = b * T_DIM + p * 256 + j * 64 + tid;
        out[B_DIM * D_DIM + g] = __expf(sP[g] - m) * invS;
    }
}

// ---------------------------------------------------------------------------
extern "C" void kernel_launch(void* const* d_in, const int* in_sizes, int n_in,
                              void* d_out, int out_size, void* d_ws, size_t ws_size,
                              hipStream_t stream) {
    const float* values = (const float*)d_in[0];
    const float* query  = (const float*)d_in[1];
    const float* W1_w   = (const float*)d_in[2];
    const float* W1_b   = (const float*)d_in[3];
    const float* W2_w   = (const float*)d_in[4];
    const float* W2_b   = (const float*)d_in[5];
    const float* V_w    = (const float*)d_in[6];
    // V_b (d_in[7]) dropped: softmax is shift-invariant.

    float* out = (float*)d_out;

    unsigned char* ws = (unsigned char*)d_ws;
    unsigned short* W1T = (unsigned short*)(ws);             // 512 KiB
    float* qb  = (float*)(ws + 524288);                      // 64 KiB
    float* sP  = (float*)(ws + 589824);                      // 256 KiB raw scores
    float* Pms = (float*)(ws + 851968);                      // 8 KiB (m_c, S_c)
    float* Pctx= (float*)(ws + 860160);                      // 2 MiB chunk contexts

    prep_kernel<<<384, 256, 0, stream>>>(W1_w, W1_b, W2_w, W2_b, query, W1T, qb);
    fused_kernel<<<1024, 512, 0, stream>>>(values, W1T, qb, V_w, sP, Pms, Pctx);
    combine_kernel<<<256, 64, 0, stream>>>(Pctx, Pms, sP, out);
}

// Round 8
// 260.083 us; speedup vs baseline: 1.1681x; 1.0172x over previous
//
#include <hip/hip_runtime.h>
#include <hip/hip_bf16.h>
#include <stdint.h>

// Bahdanau attention. B=32, T=2048, D=512, U=512.
// d_out: context[B,D] (16384 f32) then attention_weights[B,T,1] (65536 f32)
//
// R8 structure: 3 kernels.
//  1) prep: W1 -> bf16 W1T (MFMA layout); qb = query@W2 + biases.
//  2) fused (BM=128): A = contiguous f32->bf16 LDS staging in 4 k-quarters
//     (R6 fix: 6 TB/s pattern); B = W1T staged ONCE per block through LDS
//     slab-dbuf via global_load_lds (R0 fix: B consumed from LDS, not
//     re-read from L2/L3 -- cuts B traffic 1 GB -> 256 MB, which was the
//     R4-R7 wall: L2 thrashed by A-streams pushed B-reads to Infinity
//     Cache). Then chunk softmax partial + partial context (L2 re-read).
//  3) combine: global m,S per batch (16 chunks); rescale C_c; weights.

#define B_DIM 32
#define T_DIM 2048
#define D_DIM 512
#define U_DIM 512
#define M_DIM (B_DIM * T_DIM)   // 65536 rows

typedef short bf16x8 __attribute__((ext_vector_type(8)));
typedef float f32x4 __attribute__((ext_vector_type(4)));

__device__ __forceinline__ float fast_tanh(float x) {
    float e = __expf(2.0f * x);
    return 1.0f - __fdividef(2.0f, e + 1.0f);
}

// scalar RNE f32->bf16 (prep only)
__device__ __forceinline__ short bf16r(float x) {
    unsigned u = __float_as_uint(x);
    u += 0x7fffu + ((u >> 16) & 1u);
    return (short)(u >> 16);
}

// async global->LDS, 16B per lane (dest = wave-uniform base + lane*16;
// call sites keep lane-linear LDS addresses). Proven R0/R2/R3.
__device__ __forceinline__ void g2lds16(const void* g, void* lds) {
    auto gp = reinterpret_cast<const __attribute__((address_space(1))) unsigned int*>(
        reinterpret_cast<uintptr_t>(g));
    auto lp = reinterpret_cast<__attribute__((address_space(3))) unsigned int*>(
        (unsigned int)(uintptr_t)lds);
    __builtin_amdgcn_global_load_lds(gp, lp, 16, 0, 0);
}

// ---------------------------------------------------------------------------
// W1T layout in 16-byte units (8 bf16 along k):
//   unit n = ut*16384 + kstep*1024 + kc*256 + uu
//   where u = ut*256+uu, k = kstep*32 + kc*8 + j.  (kc == quad)
// Slab(ks) = the two 1024-unit runs {ut*16384 + ks*1024 ...} for ut=0,1
// -> 32 KiB, staged linearly into LDS (local unit j: ut=j>>10, idx=j&1023).
// Fragment read in LDS (R0-proven, 0 bank conflicts): wave wc: ut=wc>>1,
// unit = ut*1024 + quad*256 + (wc&1)*128 + ui*16 + l15, byte = unit*16.
// ---------------------------------------------------------------------------

// Kernel 1: prep. (unchanged)
__global__ void prep_kernel(const float* __restrict__ W1_w,
                            const float* __restrict__ W1_b,
                            const float* __restrict__ W2_w,
                            const float* __restrict__ W2_b,
                            const float* __restrict__ query,
                            unsigned short* __restrict__ W1T,
                            float* __restrict__ qb) {
    __shared__ float red[256];
    const int tid = threadIdx.x;
    if (blockIdx.x < 128) {
        int n = blockIdx.x * 256 + tid;   // unit id 0..32767
        int uu    = n & 255;
        int kc    = (n >> 8) & 3;
        int kstep = (n >> 10) & 15;
        int ut    = n >> 14;
        int u  = ut * 256 + uu;
        int k0 = kstep * 32 + kc * 8;
        bf16x8 pk;
#pragma unroll
        for (int j = 0; j < 8; ++j)
            pk[j] = bf16r(W1_w[(size_t)(k0 + j) * U_DIM + u]);  // coalesced in u
        ((bf16x8*)W1T)[n] = pk;
    } else {
        int bid = blockIdx.x - 128;       // 0..255
        int b  = bid >> 3;
        int ug = bid & 7;
        int u  = ug * 64 + (tid & 63);
        int dq = tid >> 6;                // 0..3 (128 d each)
        const float* q  = query + b * D_DIM + dq * 128;
        const float* w2 = W2_w + (size_t)(dq * 128) * U_DIM + u;
        float acc = 0.f;
#pragma unroll 8
        for (int d = 0; d < 128; ++d)
            acc += q[d] * w2[(size_t)d * U_DIM];
        red[tid] = acc;
        __syncthreads();
        if (tid < 64) {
            qb[b * U_DIM + u] = red[tid] + red[tid + 64] + red[tid + 128]
                              + red[tid + 192] + W2_b[u] + W1_b[u];
        }
    }
}

// ---------------------------------------------------------------------------
// Kernel 2: fused. 512 blocks x 512 thr (8 waves). Block = 128 m x 512 u.
// Waves: wr = w>>2 (0..1, 64 m each), wc = w&3 (0..3, 128 u each).
// Wave tile: acc[4][8] (4 m-tiles x 8 u-frags), 32 MFMA per 32-k slab.
//
// LDS: Abuf = one k-quarter of A (128 rows x 128 k bf16, 32 KiB), row
// stride 256 B = 16 slots of 16 B, stored slot' = slot ^ (row&7) (R6
// swizzle; frag read r=..+l15, slot=s*4+quad -> 2-way = free).
// Bbuf[2] = 32 KiB slab double-buffer (one barrier per slab).
// Schedule: stageA(q0)+stageB(0); per slab: stageB(next) | compute | sync.
// At quarter end: stageA(q+1) (8 f32x4/thread batched in flight) + sync.
// ---------------------------------------------------------------------------
__global__ __launch_bounds__(512, 2) void fused_kernel(
        const float* __restrict__ values,
        const unsigned short* __restrict__ W1T,
        const float* __restrict__ qb,
        const float* __restrict__ Vw,
        float* __restrict__ sP,
        float* __restrict__ Pms,
        float* __restrict__ Pctx) {
    __shared__ __align__(16) unsigned char Abuf[32768];      // 128 r x 256 B
    __shared__ __align__(16) unsigned char Bbuf[2][32768];   // slab dbuf
    __shared__ float sred[4][128];
    __shared__ float ew[128];
    __shared__ float redm[2];
    __shared__ float reds[2];
    __shared__ __align__(16) float red[4][512];

    const int tid  = threadIdx.x;
    const int lane = tid & 63;
    const int w    = tid >> 6;       // 0..7
    const int l15  = lane & 15;
    const int quad = lane >> 4;
    const int wr   = w >> 2;         // 0..1 : 64 m-rows each
    const int wc   = w & 3;          // 0..3 : 128 u each
    const int chunk = blockIdx.x;    // 0..511
    const int mb   = chunk * 128;
    const int b    = mb >> 11;

    const float* srcA = values + (size_t)mb * D_DIM;

    // ---- A-quarter stage: contiguous f32 read -> bf16 -> swizzled LDS ----
    // quarter q covers k in [q*128, q*128+128). 8 f32x4 per thread, all
    // issued before first use (batched in flight).
    auto stageA = [&](int q) {
        f32x4 v[8];
#pragma unroll
        for (int it = 0; it < 8; ++it) {
            int idx = it * 2048 + tid * 4;       // 0..16383
            int row = idx >> 7;                  // 0..127
            int kq  = idx & 127;
            v[it] = *(const f32x4*)(srcA + (size_t)row * D_DIM + q * 128 + kq);
        }
#pragma unroll
        for (int it = 0; it < 8; ++it) {
            int idx = it * 2048 + tid * 4;
            int row = idx >> 7;
            int kq  = idx & 127;
            union { __hip_bfloat162 h[2]; unsigned long long u; } pk;
            pk.h[0] = __float22bfloat162_rn(make_float2(v[it][0], v[it][1]));
            pk.h[1] = __float22bfloat162_rn(make_float2(v[it][2], v[it][3]));
            int addr = row * 256 + ((((kq >> 3) ^ (row & 7)) << 4) | ((kq & 7) * 2));
            *(unsigned long long*)(Abuf + addr) = pk.u;
        }
    };
    // ---- B-slab stage: 32 KiB via global_load_lds, lane-linear ----
    auto stageB = [&](int slab, int buf) {
#pragma unroll
        for (int i = 0; i < 4; ++i) {
            int j = i * 512 + tid;               // 0..2047 local unit
            int ug = (j >> 10) * 16384 + slab * 1024 + (j & 1023);
            g2lds16(W1T + (size_t)ug * 8, Bbuf[buf] + j * 16);
        }
    };

    stageA(0);
    stageB(0, 0);
    __syncthreads();

    // per-wave B fragment base byte offset in a slab buffer
    const int bfo = (((wc >> 1) * 1024 + quad * 256 + (wc & 1) * 128 + l15) << 4);
    const int ra[4] = { wr * 64 + l15,      wr * 64 + 16 + l15,
                        wr * 64 + 32 + l15, wr * 64 + 48 + l15 };

    f32x4 acc[4][8] = {};
    int sel = 0;

#pragma unroll 1
    for (int q = 0; q < 4; ++q) {
#pragma unroll 1
        for (int s = 0; s < 4; ++s) {
            const int slab = q * 4 + s;
            if (slab < 15) stageB(slab + 1, sel ^ 1);

            // fragments
            bf16x8 bfr[8];
#pragma unroll
            for (int ui = 0; ui < 8; ++ui)
                bfr[ui] = *(const bf16x8*)(Bbuf[sel] + bfo + ui * 256);
            const int slot = s * 4 + quad;
            bf16x8 af[4];
#pragma unroll
            for (int mt = 0; mt < 4; ++mt)
                af[mt] = *(const bf16x8*)(Abuf + ra[mt] * 256 + ((slot ^ (ra[mt] & 7)) << 4));

            __builtin_amdgcn_sched_barrier(0);
            __builtin_amdgcn_s_setprio(1);
#pragma unroll
            for (int ui = 0; ui < 8; ++ui) {
#pragma unroll
                for (int mt = 0; mt < 4; ++mt)
                    acc[mt][ui] = __builtin_amdgcn_mfma_f32_16x16x32_bf16(
                        af[mt], bfr[ui], acc[mt][ui], 0, 0, 0);
            }
            __builtin_amdgcn_s_setprio(0);
            __builtin_amdgcn_sched_barrier(0);

            __syncthreads();      // drains B-stage; publishes Bbuf[sel^1]
            sel ^= 1;
        }
        if (q < 3) {
            stageA(q + 1);        // Abuf reads all done (last sync)
            __syncthreads();
        }
    }

    // ---- per-wave u-slice score partial: tanh + Vw, reduce over u ----
    const int ub = wc * 128 + l15;
    float smv[4][4] = {};
#pragma unroll
    for (int ui = 0; ui < 8; ++ui) {
        const int u = ub + ui * 16;
        const float qv = qb[b * U_DIM + u];
        const float vw = Vw[u];
#pragma unroll
        for (int mt = 0; mt < 4; ++mt)
#pragma unroll
            for (int r = 0; r < 4; ++r)
                smv[mt][r] += fast_tanh(acc[mt][ui][r] + qv) * vw;
    }
#pragma unroll
    for (int mt = 0; mt < 4; ++mt)
#pragma unroll
        for (int r = 0; r < 4; ++r) {
            float v = smv[mt][r];
            v += __shfl_xor(v, 1, 64);
            v += __shfl_xor(v, 2, 64);
            v += __shfl_xor(v, 4, 64);
            v += __shfl_xor(v, 8, 64);
            smv[mt][r] = v;
        }
    if (l15 == 0) {
#pragma unroll
        for (int mt = 0; mt < 4; ++mt)
#pragma unroll
            for (int r = 0; r < 4; ++r)
                sred[wc][wr * 64 + mt * 16 + quad * 4 + r] = smv[mt][r];
    }
    __syncthreads();

    // ---- chunk softmax partial over 128 rows (2 waves) ----
    float s = 0.f;
    if (tid < 128) {
        s = sred[0][tid] + sred[1][tid] + sred[2][tid] + sred[3][tid];
        sP[mb + tid] = s;
        float m = s;
#pragma unroll
        for (int off = 1; off < 64; off <<= 1)
            m = fmaxf(m, __shfl_xor(m, off, 64));
        if ((tid & 63) == 0) redm[tid >> 6] = m;
    }
    __syncthreads();
    const float mc = fmaxf(redm[0], redm[1]);
    if (tid < 128) {
        float e = __expf(s - mc);
        ew[tid] = e;
        float S = e;
#pragma unroll
        for (int off = 1; off < 64; off <<= 1)
            S += __shfl_xor(S, off, 64);
        if ((tid & 63) == 0) reds[tid >> 6] = S;
    }
    __syncthreads();
    if (tid == 0) { Pms[chunk * 2] = mc; Pms[chunk * 2 + 1] = reds[0] + reds[1]; }

    // ---- partial context: C_c[d] = sum_t e_t * v[t,d]; v rows hit L2 ----
    {
        const int d4 = tid & 127;    // float4 column (512 floats)
        const int th = tid >> 7;     // 0..3 : 32 contiguous rows each
        const float4* vb = (const float4*)(values + (size_t)(mb + th * 32) * D_DIM) + d4;
        float4 a = {0.f, 0.f, 0.f, 0.f};
#pragma unroll
        for (int i = 0; i < 32; ++i) {
            float e = ew[th * 32 + i];
            float4 v = vb[(size_t)i * 128];
            a.x += e * v.x; a.y += e * v.y;
            a.z += e * v.z; a.w += e * v.w;
        }
        ((float4*)red)[th * 128 + d4] = a;
    }
    __syncthreads();
    if (tid < 128) {
        float4 o0 = ((float4*)red)[tid];
        float4 o1 = ((float4*)red)[128 + tid];
        float4 o2 = ((float4*)red)[256 + tid];
        float4 o3 = ((float4*)red)[384 + tid];
        float4 o;
        o.x = o0.x + o1.x + o2.x + o3.x;
        o.y = o0.y + o1.y + o2.y + o3.y;
        o.z = o0.z + o1.z + o2.z + o3.z;
        o.w = o0.w + o1.w + o2.w + o3.w;
        *(float4*)(Pctx + (size_t)chunk * 512 + tid * 4) = o;
    }
}

// ---------------------------------------------------------------------------
// Kernel 3: combine. 256 blocks x 64 thr: b = bid>>3, part p = bid&7.
// Global m,S from 16 chunk partials (128 rows each); context d-slice
// p*64..p*64+63; weights t-slice p*256..p*256+255.
// ---------------------------------------------------------------------------
__global__ void combine_kernel(const float* __restrict__ Pctx,
                               const float* __restrict__ Pms,
                               const float* __restrict__ sP,
                               float* __restrict__ out) {
    const int bid = blockIdx.x;
    const int b   = bid >> 3;
    const int p   = bid & 7;
    const int tid = threadIdx.x;    // 0..63

    float m = -1e30f;
#pragma unroll
    for (int c = 0; c < 16; ++c)
        m = fmaxf(m, Pms[(b * 16 + c) * 2]);
    float ec[16];
    float S = 0.f;
#pragma unroll
    for (int c = 0; c < 16; ++c) {
        ec[c] = __expf(Pms[(b * 16 + c) * 2] - m);
        S += ec[c] * Pms[(b * 16 + c) * 2 + 1];
    }
    const float invS = 1.0f / S;

    // context slice
    {
        const int d = p * 64 + tid;
        float a = 0.f;
#pragma unroll
        for (int c = 0; c < 16; ++c)
            a += ec[c] * Pctx[(size_t)(b * 16 + c) * 512 + d];
        out[b * D_DIM + d] = a * invS;
    }
    // weights slice (256 t per block, coalesced)
#pragma unroll
    for (int j = 0; j < 4; ++j) {
        const int g = b * T_DIM + p * 256 + j * 64 + tid;
        out[B_DIM * D_DIM + g] = __expf(sP[g] - m) * invS;
    }
}

// ---------------------------------------------------------------------------
extern "C" void kernel_launch(void* const* d_in, const int* in_sizes, int n_in,
                              void* d_out, int out_size, void* d_ws, size_t ws_size,
                              hipStream_t stream) {
    const float* values = (const float*)d_in[0];
    const float* query  = (const float*)d_in[1];
    const float* W1_w   = (const float*)d_in[2];
    const float* W1_b   = (const float*)d_in[3];
    const float* W2_w   = (const float*)d_in[4];
    const float* W2_b   = (const float*)d_in[5];
    const float* V_w    = (const float*)d_in[6];
    // V_b (d_in[7]) dropped: softmax is shift-invariant.

    float* out = (float*)d_out;

    unsigned char* ws = (unsigned char*)d_ws;
    unsigned short* W1T = (unsigned short*)(ws);             // 512 KiB
    float* qb  = (float*)(ws + 524288);                      // 64 KiB
    float* sP  = (float*)(ws + 589824);                      // 256 KiB raw scores
    float* Pms = (float*)(ws + 851968);                      // 4 KiB (m_c, S_c)
    float* Pctx= (float*)(ws + 860160);                      // 1 MiB chunk contexts

    prep_kernel<<<384, 256, 0, stream>>>(W1_w, W1_b, W2_w, W2_b, query, W1T, qb);
    fused_kernel<<<512, 512, 0, stream>>>(values, W1T, qb, V_w, sP, Pms, Pctx);
    combine_kernel<<<256, 64, 0, stream>>>(Pctx, Pms, sP, out);
}